// Round 1
// baseline (760.799 us; speedup 1.0000x reference)
//
#include <hip/hip_runtime.h>
#include <hip/hip_bf16.h>

typedef __attribute__((ext_vector_type(4))) float f32x4;
typedef __attribute__((ext_vector_type(8))) short s16x8;
typedef __attribute__((ext_vector_type(4))) short s16x4;
typedef unsigned short u16;

#define NEXP 8
#define DD 1024
#define FF 4096
#define NTOK 8192
#define BM 128
#define BK 32
#define LDST 36   // LDS row stride in bf16 elems (72B, odd word stride)

// meta layout (int indices into workspace)
#define M_CNT 0
#define M_OFF 8
#define M_CNT2 16
#define M_NT 24
#define M_TE 32        // tile -> expert [128]
#define M_TB 160       // tile -> slot base [128]
#define M_PERM 288     // [8192] slot -> token
#define M_EIDX (288 + 8192)
#define HBUF_OFF_BYTES (1 << 17)

__device__ inline u16 f2b(float f) {
    union { float f; unsigned u; } v; v.f = f;
    unsigned r = v.u + 0x7FFF + ((v.u >> 16) & 1);   // RTN-even
    return (u16)(r >> 16);
}

__global__ void k_zero(int* meta) {
    if (threadIdx.x < 32) meta[threadIdx.x] = 0;
}

__global__ __launch_bounds__(256) void k_router(const float* __restrict__ x,
                                                const float* __restrict__ wr,
                                                const float* __restrict__ br,
                                                int* __restrict__ meta) {
    int wid = threadIdx.x >> 6, lane = threadIdx.x & 63;
    int tok = blockIdx.x * 4 + wid;
    const float* xr = x + (size_t)tok * DD;
    double s = 0.0;
    #pragma unroll
    for (int j = 0; j < 16; ++j) {
        int idx = j * 64 + lane;
        s += (double)xr[idx] * (double)wr[idx];
    }
    #pragma unroll
    for (int off = 32; off > 0; off >>= 1) s += __shfl_down(s, off);
    if (lane == 0) {
        double key = s + (double)br[0];
        int e = ((int)floor(key)) & 7;   // two's-complement & == mod 8 (non-neg)
        meta[M_EIDX + tok] = e;
        atomicAdd(meta + M_CNT + e, 1);
    }
}

__global__ void k_scan(int* meta) {
    if (threadIdx.x == 0) {
        int off = 0, tt = 0;
        for (int e = 0; e < NEXP; ++e) {
            meta[M_OFF + e] = off;
            int c = meta[M_CNT + e];
            int nt = (c + BM - 1) / BM;
            for (int i = 0; i < nt; ++i) {
                meta[M_TE + tt] = e;
                meta[M_TB + tt] = off + i * BM;
                ++tt;
            }
            off += c;
        }
        meta[M_NT] = tt;
    }
}

__global__ __launch_bounds__(256) void k_assign(int* __restrict__ meta) {
    int t = blockIdx.x * 256 + threadIdx.x;
    if (t < NTOK) {
        int e = meta[M_EIDX + t];
        int pos = atomicAdd(meta + M_CNT2 + e, 1);
        meta[M_PERM + meta[M_OFF + e] + pos] = t;
    }
}

// PH=1: A = x gathered via perm (fp32->bf16), B = W1[e] [K=DD][N=FF], epilogue relu -> hbuf (bf16)
// PH=2: A = hbuf (bf16),                   B = W2[e] [K=FF][N=DD], epilogue +b2 -> scatter out (fp32)
template <int PH, int KDIM, int NDIM>
__global__ __launch_bounds__(256, 2) void k_gemm(const float* __restrict__ Af,
                                                 const u16* __restrict__ Ah,
                                                 const float* __restrict__ Wsrc,
                                                 const float* __restrict__ bias,
                                                 u16* __restrict__ hout,
                                                 float* __restrict__ fout,
                                                 int* __restrict__ meta) {
    // bijective XCD-chunk swizzle: same n-block lands on same XCD
    int total = gridDim.x * gridDim.y;
    int lin = blockIdx.y * gridDim.x + blockIdx.x;
    int q = total >> 3, r = total & 7;
    int xcd = lin & 7, pos = lin >> 3;
    int sw = (xcd < r) ? (xcd * (q + 1) + pos) : (r * (q + 1) + (xcd - r) * q + pos);
    int bx = sw % gridDim.x;
    int by = sw / gridDim.x;

    if (bx >= meta[M_NT]) return;
    int e = meta[M_TE + bx];
    int sb = meta[M_TB + bx];
    int send = meta[M_OFF + e] + meta[M_CNT + e];
    const int* perm = meta + M_PERM;
    int nb = by * 128;

    const float* W = Wsrc + (size_t)e * KDIM * NDIM;

    __shared__ u16 Als[2][BM * LDST];
    __shared__ u16 Bls[2][128 * LDST];

    int t = threadIdx.x;
    int lane = t & 63;
    int wid = t >> 6;
    int wrw = wid >> 1, wcw = wid & 1;
    int lg = lane >> 4, lr = lane & 15;

    // ---- A staging coords: rows am, am+64; 8 k's at ak
    int am = t >> 2;
    int ak = (t & 3) * 8;
    int s0 = sb + am, s1 = s0 + 64;
    bool v0 = s0 < send, v1 = s1 < send;
    const float* arow0f = nullptr; const float* arow1f = nullptr;
    const u16* arow0h = nullptr; const u16* arow1h = nullptr;
    if constexpr (PH == 1) {
        arow0f = Af + (size_t)(v0 ? perm[s0] : 0) * KDIM;
        arow1f = Af + (size_t)(v1 ? perm[s1] : 0) * KDIM;
    } else {
        arow0h = Ah + (size_t)s0 * KDIM;
        arow1h = Ah + (size_t)s1 * KDIM;
    }

    // ---- B staging coords: one n-column per thread, 4 k-quads
    int bn = t & 127;
    int bq0 = (t >> 7);   // quads bq0 + 2j, j=0..3
    const float* Wcol = W + nb + bn;

    f32x4 ga4[4];      // PH1 A staging regs
    s16x8 gah[2];      // PH2 A staging regs
    float gb[16];      // B staging regs

    f32x4 acc[4][4];
    #pragma unroll
    for (int i = 0; i < 4; ++i)
        #pragma unroll
        for (int j = 0; j < 4; ++j) acc[i][j] = (f32x4){0.f, 0.f, 0.f, 0.f};

    const int NK = KDIM / BK;

    auto loadAB = [&](int kt) {
        int k0 = kt * BK;
        if constexpr (PH == 1) {
            f32x4 z = (f32x4){0.f, 0.f, 0.f, 0.f};
            if (v0) {
                ga4[0] = *(const f32x4*)(arow0f + k0 + ak);
                ga4[1] = *(const f32x4*)(arow0f + k0 + ak + 4);
            } else { ga4[0] = z; ga4[1] = z; }
            if (v1) {
                ga4[2] = *(const f32x4*)(arow1f + k0 + ak);
                ga4[3] = *(const f32x4*)(arow1f + k0 + ak + 4);
            } else { ga4[2] = z; ga4[3] = z; }
        } else {
            s16x8 z = (s16x8){0, 0, 0, 0, 0, 0, 0, 0};
            gah[0] = v0 ? *(const s16x8*)(arow0h + k0 + ak) : z;
            gah[1] = v1 ? *(const s16x8*)(arow1h + k0 + ak) : z;
        }
        #pragma unroll
        for (int j = 0; j < 4; ++j) {
            int qd = bq0 + 2 * j;
            const float* pb = Wcol + (size_t)(k0 + 4 * qd) * NDIM;
            gb[4 * j + 0] = pb[0];
            gb[4 * j + 1] = pb[NDIM];
            gb[4 * j + 2] = pb[2 * (size_t)NDIM];
            gb[4 * j + 3] = pb[3 * (size_t)NDIM];
        }
    };

    auto writeAB = [&](int buf) {
        u16* A = Als[buf]; u16* B = Bls[buf];
        if constexpr (PH == 1) {
            s16x4 w;
            w[0] = (short)f2b(ga4[0][0]); w[1] = (short)f2b(ga4[0][1]);
            w[2] = (short)f2b(ga4[0][2]); w[3] = (short)f2b(ga4[0][3]);
            *(s16x4*)&A[am * LDST + ak] = w;
            w[0] = (short)f2b(ga4[1][0]); w[1] = (short)f2b(ga4[1][1]);
            w[2] = (short)f2b(ga4[1][2]); w[3] = (short)f2b(ga4[1][3]);
            *(s16x4*)&A[am * LDST + ak + 4] = w;
            w[0] = (short)f2b(ga4[2][0]); w[1] = (short)f2b(ga4[2][1]);
            w[2] = (short)f2b(ga4[2][2]); w[3] = (short)f2b(ga4[2][3]);
            *(s16x4*)&A[(am + 64) * LDST + ak] = w;
            w[0] = (short)f2b(ga4[3][0]); w[1] = (short)f2b(ga4[3][1]);
            w[2] = (short)f2b(ga4[3][2]); w[3] = (short)f2b(ga4[3][3]);
            *(s16x4*)&A[(am + 64) * LDST + ak + 4] = w;
        } else {
            *(s16x4*)&A[am * LDST + ak]       = __builtin_shufflevector(gah[0], gah[0], 0, 1, 2, 3);
            *(s16x4*)&A[am * LDST + ak + 4]   = __builtin_shufflevector(gah[0], gah[0], 4, 5, 6, 7);
            *(s16x4*)&A[(am + 64) * LDST + ak]     = __builtin_shufflevector(gah[1], gah[1], 0, 1, 2, 3);
            *(s16x4*)&A[(am + 64) * LDST + ak + 4] = __builtin_shufflevector(gah[1], gah[1], 4, 5, 6, 7);
        }
        #pragma unroll
        for (int j = 0; j < 4; ++j) {
            int qd = bq0 + 2 * j;
            s16x4 w;
            w[0] = (short)f2b(gb[4 * j + 0]); w[1] = (short)f2b(gb[4 * j + 1]);
            w[2] = (short)f2b(gb[4 * j + 2]); w[3] = (short)f2b(gb[4 * j + 3]);
            *(s16x4*)&B[bn * LDST + 4 * qd] = w;
        }
    };

    auto compute = [&](int buf) {
        const u16* A = Als[buf]; const u16* B = Bls[buf];
        s16x8 af[4], bf[4];
        #pragma unroll
        for (int mi = 0; mi < 4; ++mi) {
            const s16x4* p = (const s16x4*)&A[(wrw * 64 + mi * 16 + lr) * LDST + lg * 8];
            af[mi] = __builtin_shufflevector(p[0], p[1], 0, 1, 2, 3, 4, 5, 6, 7);
        }
        #pragma unroll
        for (int ni = 0; ni < 4; ++ni) {
            const s16x4* p = (const s16x4*)&B[(wcw * 64 + ni * 16 + lr) * LDST + lg * 8];
            bf[ni] = __builtin_shufflevector(p[0], p[1], 0, 1, 2, 3, 4, 5, 6, 7);
        }
        #pragma unroll
        for (int mi = 0; mi < 4; ++mi)
            #pragma unroll
            for (int ni = 0; ni < 4; ++ni)
                acc[mi][ni] = __builtin_amdgcn_mfma_f32_16x16x32_bf16(af[mi], bf[ni], acc[mi][ni], 0, 0, 0);
    };

    loadAB(0);
    for (int kt = 0; kt < NK; ++kt) {
        writeAB(kt & 1);
        __syncthreads();
        if (kt + 1 < NK) loadAB(kt + 1);
        compute(kt & 1);
    }

    // ---- epilogue
    if constexpr (PH == 1) {
        #pragma unroll
        for (int ni = 0; ni < 4; ++ni) {
            int f = nb + wcw * 64 + ni * 16 + lr;
            float bv = bias[(size_t)e * NDIM + f];
            #pragma unroll
            for (int mi = 0; mi < 4; ++mi) {
                int srow = sb + wrw * 64 + mi * 16 + lg * 4;
                #pragma unroll
                for (int j = 0; j < 4; ++j) {
                    int sr = srow + j;
                    if (sr < send) {
                        float v = acc[mi][ni][j] + bv;
                        v = v > 0.f ? v : 0.f;
                        hout[(size_t)sr * NDIM + f] = f2b(v);
                    }
                }
            }
        }
    } else {
        #pragma unroll
        for (int ni = 0; ni < 4; ++ni) {
            int d = nb + wcw * 64 + ni * 16 + lr;
            float bv = bias[(size_t)e * NDIM + d];
            #pragma unroll
            for (int mi = 0; mi < 4; ++mi) {
                int srow = sb + wrw * 64 + mi * 16 + lg * 4;
                #pragma unroll
                for (int j = 0; j < 4; ++j) {
                    int sr = srow + j;
                    if (sr < send) {
                        fout[(size_t)perm[sr] * NDIM + d] = acc[mi][ni][j] + bv;
                    }
                }
            }
        }
    }
}

extern "C" void kernel_launch(void* const* d_in, const int* in_sizes, int n_in,
                              void* d_out, int out_size, void* d_ws, size_t ws_size,
                              hipStream_t stream) {
    const float* x  = (const float*)d_in[0];
    const float* wr = (const float*)d_in[1];
    const float* br = (const float*)d_in[2];
    const float* W1 = (const float*)d_in[3];
    const float* b1 = (const float*)d_in[4];
    const float* W2 = (const float*)d_in[5];
    const float* b2 = (const float*)d_in[6];
    float* out = (float*)d_out;
    int* meta = (int*)d_ws;
    u16* hbuf = (u16*)((char*)d_ws + HBUF_OFF_BYTES);

    k_zero<<<1, 64, 0, stream>>>(meta);
    k_router<<<NTOK / 4, 256, 0, stream>>>(x, wr, br, meta);
    k_scan<<<1, 64, 0, stream>>>(meta);
    k_assign<<<NTOK / 256, 256, 0, stream>>>(meta);
    k_gemm<1, DD, FF><<<dim3(72, FF / 128), 256, 0, stream>>>(x, nullptr, W1, b1, hbuf, nullptr, meta);
    k_gemm<2, FF, DD><<<dim3(72, DD / 128), 256, 0, stream>>>(nullptr, hbuf, W2, b2, nullptr, out, meta);
}

// Round 2
// 701.019 us; speedup vs baseline: 1.0853x; 1.0853x over previous
//
#include <hip/hip_runtime.h>
#include <hip/hip_bf16.h>

typedef __attribute__((ext_vector_type(4))) float f32x4;
typedef __attribute__((ext_vector_type(8))) short s16x8;
typedef __attribute__((ext_vector_type(4))) short s16x4;
typedef unsigned short u16;

#define NEXP 8
#define DD 1024
#define FF 4096
#define NTOK 8192
#define BM 128
#define BK 32
#define LDST 36   // fallback-kernel LDS stride

// meta layout (int indices into workspace)
#define M_CNT 0
#define M_OFF 8
#define M_CNT2 16
#define M_NT 24
#define M_TE 32        // tile -> expert [128]
#define M_TB 160       // tile -> slot base [128]
#define M_PERM 288     // [8192] slot -> token
#define M_EIDX (288 + 8192)
#define HBUF_OFF_BYTES (1 << 17)

__device__ __forceinline__ u16 f2b(float f) {
    union { float f; unsigned u; } v; v.f = f;
    unsigned r = v.u + 0x7FFF + ((v.u >> 16) & 1);   // RTN-even
    return (u16)(r >> 16);
}

__device__ __forceinline__ void gload16(const u16* g, u16* l) {
    __builtin_amdgcn_global_load_lds(
        (const __attribute__((address_space(1))) void*)g,
        (__attribute__((address_space(3))) void*)l, 16, 0, 0);
}

__global__ void k_zero(int* meta) {
    if (threadIdx.x < 32) meta[threadIdx.x] = 0;
}

__global__ __launch_bounds__(256) void k_router(const float* __restrict__ x,
                                                const float* __restrict__ wr,
                                                const float* __restrict__ br,
                                                int* __restrict__ meta) {
    int wid = threadIdx.x >> 6, lane = threadIdx.x & 63;
    int tok = blockIdx.x * 4 + wid;
    const float* xr = x + (size_t)tok * DD;
    double s = 0.0;
    #pragma unroll
    for (int j = 0; j < 16; ++j) {
        int idx = j * 64 + lane;
        s += (double)xr[idx] * (double)wr[idx];
    }
    #pragma unroll
    for (int off = 32; off > 0; off >>= 1) s += __shfl_down(s, off);
    if (lane == 0) {
        double key = s + (double)br[0];
        int e = ((int)floor(key)) & 7;   // two's-complement & == mod 8 (non-neg)
        meta[M_EIDX + tok] = e;
        atomicAdd(meta + M_CNT + e, 1);
    }
}

__global__ void k_scan(int* meta) {
    if (threadIdx.x == 0) {
        int off = 0, tt = 0;
        for (int e = 0; e < NEXP; ++e) {
            meta[M_OFF + e] = off;
            int c = meta[M_CNT + e];
            int nt = (c + BM - 1) / BM;
            for (int i = 0; i < nt; ++i) {
                meta[M_TE + tt] = e;
                meta[M_TB + tt] = off + i * BM;
                ++tt;
            }
            off += c;
        }
        meta[M_NT] = tt;
    }
}

__global__ __launch_bounds__(256) void k_assign(int* __restrict__ meta) {
    int t = blockIdx.x * 256 + threadIdx.x;
    if (t < NTOK) {
        int e = meta[M_EIDX + t];
        int pos = atomicAdd(meta + M_CNT2 + e, 1);
        meta[M_PERM + meta[M_OFF + e] + pos] = t;
    }
}

// ---------------- converters (fast path) ----------------

// x fp32 -> bf16, elementwise, 8 elems/thread
__global__ __launch_bounds__(256) void k_cvtx(const float* __restrict__ in, u16* __restrict__ out) {
    size_t i = ((size_t)blockIdx.x * 256 + threadIdx.x) * 8;
    f32x4 a = *(const f32x4*)(in + i);
    f32x4 b = *(const f32x4*)(in + i + 4);
    s16x8 o;
    o[0] = (short)f2b(a[0]); o[1] = (short)f2b(a[1]); o[2] = (short)f2b(a[2]); o[3] = (short)f2b(a[3]);
    o[4] = (short)f2b(b[0]); o[5] = (short)f2b(b[1]); o[6] = (short)f2b(b[2]); o[7] = (short)f2b(b[3]);
    *(s16x8*)(out + i) = o;
}

// per-expert transpose+convert: in[e][R][C] fp32 -> out[e][C][R] bf16
// grid: (C/64, R/64, E), block 256
__global__ __launch_bounds__(256) void k_cvtT(const float* __restrict__ in, u16* __restrict__ out,
                                              int R, int C) {
    __shared__ u16 tile[64][72];
    int e = blockIdx.z;
    const float* src = in + (size_t)e * R * C;
    u16* dst = out + (size_t)e * R * C;
    int r0 = blockIdx.y * 64, c0 = blockIdx.x * 64;
    int t = threadIdx.x;
    int tr = t >> 4;           // 0..15
    int tc = (t & 15) * 4;     // 0..60
    #pragma unroll
    for (int i = 0; i < 4; ++i) {
        int r = tr + i * 16;
        f32x4 v = *(const f32x4*)(src + (size_t)(r0 + r) * C + c0 + tc);
        tile[r][tc + 0] = f2b(v[0]);
        tile[r][tc + 1] = f2b(v[1]);
        tile[r][tc + 2] = f2b(v[2]);
        tile[r][tc + 3] = f2b(v[3]);
    }
    __syncthreads();
    #pragma unroll
    for (int i = 0; i < 4; ++i) {
        int cr = tr + i * 16;
        s16x4 w;
        w[0] = tile[tc + 0][cr];
        w[1] = tile[tc + 1][cr];
        w[2] = tile[tc + 2][cr];
        w[3] = tile[tc + 3][cr];
        *(s16x4*)(dst + (size_t)(c0 + cr) * R + r0 + tc) = w;
    }
}

// ---------------- fast GEMM: all-bf16, global_load_lds, XOR swizzle ----------------
// A: [rows][KDIM] bf16 (PH1: xh gathered via perm; PH2: hbuf, grouped order)
// B: WT [e][NDIM][KDIM] bf16 (pre-transposed: n-major, k-contiguous)
// PH1 epilogue: relu(+b1) -> hbuf bf16.  PH2: +b2 -> scatter fp32 out via perm.
template <int PH, int KDIM, int NDIM>
__global__ __launch_bounds__(256, 2) void k_gemm2(const u16* __restrict__ Ah,
                                                  const u16* __restrict__ WT,
                                                  const float* __restrict__ bias,
                                                  u16* __restrict__ hout,
                                                  float* __restrict__ fout,
                                                  int* __restrict__ meta) {
    // bijective XCD swizzle (total % 8 == 0 for our grids): same by-panel per XCD
    int total = gridDim.x * gridDim.y;
    int lin = blockIdx.y * gridDim.x + blockIdx.x;
    int q = total >> 3;
    int sw = (lin & 7) * q + (lin >> 3);
    int bx = sw % gridDim.x;
    int by = sw / gridDim.x;

    if (bx >= meta[M_NT]) return;
    int e = meta[M_TE + bx];
    int sb = meta[M_TB + bx];
    int send = meta[M_OFF + e] + meta[M_CNT + e];
    const int* perm = meta + M_PERM;
    int nb = by * 128;

    __shared__ __attribute__((aligned(16))) u16 As[128 * 64];  // [row][64k], slot-swizzled
    __shared__ __attribute__((aligned(16))) u16 Bs[128 * 64];  // [n][64k],  slot-swizzled

    int t = threadIdx.x;
    int lane = t & 63;
    int wid = t >> 6;
    int l3 = lane >> 3;        // row within 8-row chunk
    int ssl = (lane & 7) ^ l3; // source 16B-slot (inverse swizzle; row&7 == l3)

    // staging source pointers: 4 chunks of 8 rows per wave, for A and B
    const u16* srcA[4];
    const u16* srcB[4];
    #pragma unroll
    for (int i = 0; i < 4; ++i) {
        int row = wid * 32 + i * 8 + l3;
        int s = sb + row; if (s >= send) s = send - 1;
        int tok = (PH == 1) ? perm[s] : s;
        srcA[i] = Ah + (size_t)tok * KDIM + ssl * 8;
        srcB[i] = WT + ((size_t)e * NDIM + (nb + row)) * KDIM + ssl * 8;
    }

    int wrw = wid >> 1, wcw = wid & 1;
    int lr = lane & 15, lg = lane >> 4;

    f32x4 acc[4][4];
    #pragma unroll
    for (int i = 0; i < 4; ++i)
        #pragma unroll
        for (int j = 0; j < 4; ++j) acc[i][j] = (f32x4){0.f, 0.f, 0.f, 0.f};

    const int NK = KDIM / 64;
    for (int kt = 0; kt < NK; ++kt) {
        int k0 = kt * 64;
        // stage: 8 x global_load_lds_dwordx4 (wave-uniform LDS base, per-lane global src)
        #pragma unroll
        for (int i = 0; i < 4; ++i)
            gload16(srcA[i] + k0, &As[(wid * 4 + i) * 512]);
        #pragma unroll
        for (int i = 0; i < 4; ++i)
            gload16(srcB[i] + k0, &Bs[(wid * 4 + i) * 512]);
        __syncthreads();   // drains vmcnt (global_load_lds) per __syncthreads semantics

        #pragma unroll
        for (int ks = 0; ks < 2; ++ks) {
            s16x8 af[4], bf[4];
            #pragma unroll
            for (int mi = 0; mi < 4; ++mi) {
                int r = wrw * 64 + mi * 16 + lr;
                int sd = (ks * 4 + lg) ^ (r & 7);
                af[mi] = *(const s16x8*)&As[r * 64 + sd * 8];
            }
            #pragma unroll
            for (int ni = 0; ni < 4; ++ni) {
                int r = wcw * 64 + ni * 16 + lr;
                int sd = (ks * 4 + lg) ^ (r & 7);
                bf[ni] = *(const s16x8*)&Bs[r * 64 + sd * 8];
            }
            #pragma unroll
            for (int mi = 0; mi < 4; ++mi)
                #pragma unroll
                for (int ni = 0; ni < 4; ++ni)
                    acc[mi][ni] = __builtin_amdgcn_mfma_f32_16x16x32_bf16(af[mi], bf[ni], acc[mi][ni], 0, 0, 0);
        }
        __syncthreads();   // all waves done reading before next stage overwrites
    }

    // ---- epilogue (C/D map: col=lane&15, row=(lane>>4)*4+reg — m89-verified)
    if constexpr (PH == 1) {
        #pragma unroll
        for (int ni = 0; ni < 4; ++ni) {
            int f = nb + wcw * 64 + ni * 16 + lr;
            float bv = bias[(size_t)e * NDIM + f];
            #pragma unroll
            for (int mi = 0; mi < 4; ++mi) {
                int srow = sb + wrw * 64 + mi * 16 + lg * 4;
                #pragma unroll
                for (int j = 0; j < 4; ++j) {
                    int sr = srow + j;
                    if (sr < send) {
                        float v = acc[mi][ni][j] + bv;
                        v = v > 0.f ? v : 0.f;
                        hout[(size_t)sr * NDIM + f] = f2b(v);
                    }
                }
            }
        }
    } else {
        #pragma unroll
        for (int ni = 0; ni < 4; ++ni) {
            int d = nb + wcw * 64 + ni * 16 + lr;
            float bv = bias[(size_t)e * NDIM + d];
            #pragma unroll
            for (int mi = 0; mi < 4; ++mi) {
                int srow = sb + wrw * 64 + mi * 16 + lg * 4;
                #pragma unroll
                for (int j = 0; j < 4; ++j) {
                    int sr = srow + j;
                    if (sr < send) {
                        fout[(size_t)perm[sr] * NDIM + d] = acc[mi][ni][j] + bv;
                    }
                }
            }
        }
    }
}

// ---------------- fallback GEMM (round-1, reg-staged fp32->bf16) ----------------
template <int PH, int KDIM, int NDIM>
__global__ __launch_bounds__(256, 2) void k_gemm_fb(const float* __restrict__ Af,
                                                    const u16* __restrict__ Ah,
                                                    const float* __restrict__ Wsrc,
                                                    const float* __restrict__ bias,
                                                    u16* __restrict__ hout,
                                                    float* __restrict__ fout,
                                                    int* __restrict__ meta) {
    int total = gridDim.x * gridDim.y;
    int lin = blockIdx.y * gridDim.x + blockIdx.x;
    int q = total >> 3, r = total & 7;
    int xcd = lin & 7, pos = lin >> 3;
    int sw = (xcd < r) ? (xcd * (q + 1) + pos) : (r * (q + 1) + (xcd - r) * q + pos);
    int bx = sw % gridDim.x;
    int by = sw / gridDim.x;

    if (bx >= meta[M_NT]) return;
    int e = meta[M_TE + bx];
    int sb = meta[M_TB + bx];
    int send = meta[M_OFF + e] + meta[M_CNT + e];
    const int* perm = meta + M_PERM;
    int nb = by * 128;

    const float* W = Wsrc + (size_t)e * KDIM * NDIM;

    __shared__ u16 Als[2][BM * LDST];
    __shared__ u16 Bls[2][128 * LDST];

    int t = threadIdx.x;
    int lane = t & 63;
    int wid = t >> 6;
    int wrw = wid >> 1, wcw = wid & 1;
    int lg = lane >> 4, lr = lane & 15;

    int am = t >> 2;
    int ak = (t & 3) * 8;
    int s0 = sb + am, s1 = s0 + 64;
    bool v0 = s0 < send, v1 = s1 < send;
    const float* arow0f = nullptr; const float* arow1f = nullptr;
    const u16* arow0h = nullptr; const u16* arow1h = nullptr;
    if constexpr (PH == 1) {
        arow0f = Af + (size_t)(v0 ? perm[s0] : 0) * KDIM;
        arow1f = Af + (size_t)(v1 ? perm[s1] : 0) * KDIM;
    } else {
        arow0h = Ah + (size_t)s0 * KDIM;
        arow1h = Ah + (size_t)s1 * KDIM;
    }

    int bn = t & 127;
    int bq0 = (t >> 7);
    const float* Wcol = W + nb + bn;

    f32x4 ga4[4];
    s16x8 gah[2];
    float gb[16];

    f32x4 acc[4][4];
    #pragma unroll
    for (int i = 0; i < 4; ++i)
        #pragma unroll
        for (int j = 0; j < 4; ++j) acc[i][j] = (f32x4){0.f, 0.f, 0.f, 0.f};

    const int NK = KDIM / BK;

    auto loadAB = [&](int kt) {
        int k0 = kt * BK;
        if constexpr (PH == 1) {
            f32x4 z = (f32x4){0.f, 0.f, 0.f, 0.f};
            if (v0) {
                ga4[0] = *(const f32x4*)(arow0f + k0 + ak);
                ga4[1] = *(const f32x4*)(arow0f + k0 + ak + 4);
            } else { ga4[0] = z; ga4[1] = z; }
            if (v1) {
                ga4[2] = *(const f32x4*)(arow1f + k0 + ak);
                ga4[3] = *(const f32x4*)(arow1f + k0 + ak + 4);
            } else { ga4[2] = z; ga4[3] = z; }
        } else {
            s16x8 z = (s16x8){0, 0, 0, 0, 0, 0, 0, 0};
            gah[0] = v0 ? *(const s16x8*)(arow0h + k0 + ak) : z;
            gah[1] = v1 ? *(const s16x8*)(arow1h + k0 + ak) : z;
        }
        #pragma unroll
        for (int j = 0; j < 4; ++j) {
            int qd = bq0 + 2 * j;
            const float* pb = Wcol + (size_t)(k0 + 4 * qd) * NDIM;
            gb[4 * j + 0] = pb[0];
            gb[4 * j + 1] = pb[NDIM];
            gb[4 * j + 2] = pb[2 * (size_t)NDIM];
            gb[4 * j + 3] = pb[3 * (size_t)NDIM];
        }
    };

    auto writeAB = [&](int buf) {
        u16* A = Als[buf]; u16* B = Bls[buf];
        if constexpr (PH == 1) {
            s16x4 w;
            w[0] = (short)f2b(ga4[0][0]); w[1] = (short)f2b(ga4[0][1]);
            w[2] = (short)f2b(ga4[0][2]); w[3] = (short)f2b(ga4[0][3]);
            *(s16x4*)&A[am * LDST + ak] = w;
            w[0] = (short)f2b(ga4[1][0]); w[1] = (short)f2b(ga4[1][1]);
            w[2] = (short)f2b(ga4[1][2]); w[3] = (short)f2b(ga4[1][3]);
            *(s16x4*)&A[am * LDST + ak + 4] = w;
            w[0] = (short)f2b(ga4[2][0]); w[1] = (short)f2b(ga4[2][1]);
            w[2] = (short)f2b(ga4[2][2]); w[3] = (short)f2b(ga4[2][3]);
            *(s16x4*)&A[(am + 64) * LDST + ak] = w;
            w[0] = (short)f2b(ga4[3][0]); w[1] = (short)f2b(ga4[3][1]);
            w[2] = (short)f2b(ga4[3][2]); w[3] = (short)f2b(ga4[3][3]);
            *(s16x4*)&A[(am + 64) * LDST + ak + 4] = w;
        } else {
            *(s16x4*)&A[am * LDST + ak]       = __builtin_shufflevector(gah[0], gah[0], 0, 1, 2, 3);
            *(s16x4*)&A[am * LDST + ak + 4]   = __builtin_shufflevector(gah[0], gah[0], 4, 5, 6, 7);
            *(s16x4*)&A[(am + 64) * LDST + ak]     = __builtin_shufflevector(gah[1], gah[1], 0, 1, 2, 3);
            *(s16x4*)&A[(am + 64) * LDST + ak + 4] = __builtin_shufflevector(gah[1], gah[1], 4, 5, 6, 7);
        }
        #pragma unroll
        for (int j = 0; j < 4; ++j) {
            int qd = bq0 + 2 * j;
            s16x4 w;
            w[0] = (short)f2b(gb[4 * j + 0]); w[1] = (short)f2b(gb[4 * j + 1]);
            w[2] = (short)f2b(gb[4 * j + 2]); w[3] = (short)f2b(gb[4 * j + 3]);
            *(s16x4*)&B[bn * LDST + 4 * qd] = w;
        }
    };

    auto compute = [&](int buf) {
        const u16* A = Als[buf]; const u16* B = Bls[buf];
        s16x8 af[4], bf[4];
        #pragma unroll
        for (int mi = 0; mi < 4; ++mi) {
            const s16x4* p = (const s16x4*)&A[(wrw * 64 + mi * 16 + lr) * LDST + lg * 8];
            af[mi] = __builtin_shufflevector(p[0], p[1], 0, 1, 2, 3, 4, 5, 6, 7);
        }
        #pragma unroll
        for (int ni = 0; ni < 4; ++ni) {
            const s16x4* p = (const s16x4*)&B[(wcw * 64 + ni * 16 + lr) * LDST + lg * 8];
            bf[ni] = __builtin_shufflevector(p[0], p[1], 0, 1, 2, 3, 4, 5, 6, 7);
        }
        #pragma unroll
        for (int mi = 0; mi < 4; ++mi)
            #pragma unroll
            for (int ni = 0; ni < 4; ++ni)
                acc[mi][ni] = __builtin_amdgcn_mfma_f32_16x16x32_bf16(af[mi], bf[ni], acc[mi][ni], 0, 0, 0);
    };

    loadAB(0);
    for (int kt = 0; kt < NK; ++kt) {
        writeAB(kt & 1);
        __syncthreads();
        if (kt + 1 < NK) loadAB(kt + 1);
        compute(kt & 1);
    }

    if constexpr (PH == 1) {
        #pragma unroll
        for (int ni = 0; ni < 4; ++ni) {
            int f = nb + wcw * 64 + ni * 16 + lr;
            float bv = bias[(size_t)e * NDIM + f];
            #pragma unroll
            for (int mi = 0; mi < 4; ++mi) {
                int srow = sb + wrw * 64 + mi * 16 + lg * 4;
                #pragma unroll
                for (int j = 0; j < 4; ++j) {
                    int sr = srow + j;
                    if (sr < send) {
                        float v = acc[mi][ni][j] + bv;
                        v = v > 0.f ? v : 0.f;
                        hout[(size_t)sr * NDIM + f] = f2b(v);
                    }
                }
            }
        }
    } else {
        #pragma unroll
        for (int ni = 0; ni < 4; ++ni) {
            int d = nb + wcw * 64 + ni * 16 + lr;
            float bv = bias[(size_t)e * NDIM + d];
            #pragma unroll
            for (int mi = 0; mi < 4; ++mi) {
                int srow = sb + wrw * 64 + mi * 16 + lg * 4;
                #pragma unroll
                for (int j = 0; j < 4; ++j) {
                    int sr = srow + j;
                    if (sr < send) {
                        fout[(size_t)perm[sr] * NDIM + d] = acc[mi][ni][j] + bv;
                    }
                }
            }
        }
    }
}

extern "C" void kernel_launch(void* const* d_in, const int* in_sizes, int n_in,
                              void* d_out, int out_size, void* d_ws, size_t ws_size,
                              hipStream_t stream) {
    const float* x  = (const float*)d_in[0];
    const float* wr = (const float*)d_in[1];
    const float* br = (const float*)d_in[2];
    const float* W1 = (const float*)d_in[3];
    const float* b1 = (const float*)d_in[4];
    const float* W2 = (const float*)d_in[5];
    const float* b2 = (const float*)d_in[6];
    float* out = (float*)d_out;
    int* meta = (int*)d_ws;

    const size_t HB = (size_t)NTOK * FF * 2;       // hbuf bf16
    const size_t XB = (size_t)NTOK * DD * 2;       // xh bf16
    const size_t WB = (size_t)NEXP * DD * FF * 2;  // one transposed weight set bf16
    const size_t need = (size_t)HBUF_OFF_BYTES + HB + XB + WB;

    k_zero<<<1, 64, 0, stream>>>(meta);
    k_router<<<NTOK / 4, 256, 0, stream>>>(x, wr, br, meta);
    k_scan<<<1, 64, 0, stream>>>(meta);
    k_assign<<<NTOK / 256, 256, 0, stream>>>(meta);

    u16* hbuf = (u16*)((char*)d_ws + HBUF_OFF_BYTES);

    if (ws_size >= need) {
        u16* xh = (u16*)((char*)d_ws + HBUF_OFF_BYTES + HB);
        u16* wt = (u16*)((char*)d_ws + HBUF_OFF_BYTES + HB + XB);
        k_cvtx<<<(NTOK * DD) / (256 * 8), 256, 0, stream>>>(x, xh);
        k_cvtT<<<dim3(FF / 64, DD / 64, NEXP), 256, 0, stream>>>(W1, wt, DD, FF);
        k_gemm2<1, DD, FF><<<dim3(72, FF / 128), 256, 0, stream>>>(xh, wt, b1, hbuf, nullptr, meta);
        k_cvtT<<<dim3(DD / 64, FF / 64, NEXP), 256, 0, stream>>>(W2, wt, FF, DD);
        k_gemm2<2, FF, DD><<<dim3(72, DD / 128), 256, 0, stream>>>(hbuf, wt, b2, nullptr, out, meta);
    } else {
        k_gemm_fb<1, DD, FF><<<dim3(72, FF / 128), 256, 0, stream>>>(x, nullptr, W1, b1, hbuf, nullptr, meta);
        k_gemm_fb<2, FF, DD><<<dim3(72, DD / 128), 256, 0, stream>>>(nullptr, hbuf, W2, b2, nullptr, out, meta);
    }
}